// Round 1
// 304.978 us; speedup vs baseline: 1.8131x; 1.8131x over previous
//
#include <hip/hip_runtime.h>
#include <math.h>

typedef unsigned int u32;
typedef unsigned short u16;
typedef unsigned long long u64;

__device__ __forceinline__ u16 f2bf(float f){
  union{float f;u32 u;}v; v.f=f;
  u32 u=v.u; u += 0x7fffu + ((u>>16)&1u);
  return (u16)(u>>16);
}
__device__ __forceinline__ float gelu_exact(float z){
  return 0.5f*z*(1.f + erff(z*0.7071067811865476f));
}
// load 8 bf16 factors (one d-record, 16B) from LDS, widen to fp32
__device__ __forceinline__ void ld8(const uint4* fq, int arr, int d, float* o){
  uint4 v = fq[arr*1024 + d];
  union{u32 i;float f;}c;
  c.i = v.x<<16;        o[0]=c.f;  c.i = v.x&0xffff0000u; o[1]=c.f;
  c.i = v.y<<16;        o[2]=c.f;  c.i = v.y&0xffff0000u; o[3]=c.f;
  c.i = v.z<<16;        o[4]=c.f;  c.i = v.z&0xffff0000u; o[5]=c.f;
  c.i = v.w<<16;        o[6]=c.f;  c.i = v.w&0xffff0000u; o[7]=c.f;
}

// -------- K1: hT[col][b] = gelu_exact( LN(ada[b]) @ W1 + b1 )[col]  [1024,16] fp32 --------
__global__ __launch_bounds__(256) void k_hyper1(
    const float* __restrict__ ada, const float* __restrict__ lng, const float* __restrict__ lnb,
    const float* __restrict__ W1, const float* __restrict__ b1, float* __restrict__ hT)
{
  __shared__ float lns[1024];
  __shared__ float red[8];
  __shared__ float cmb[256];
  const int b = blockIdx.y;
  const int tid = threadIdx.x;
  float a4[4]; float s=0.f, s2=0.f;
  #pragma unroll
  for (int i=0;i<4;i++){
    float v = ada[(size_t)b*1024 + tid + 256*i];
    a4[i]=v; s+=v; s2+=v*v;
  }
  #pragma unroll
  for (int m=32;m>=1;m>>=1){ s += __shfl_xor(s,m,64); s2 += __shfl_xor(s2,m,64); }
  if ((tid&63)==0){ red[tid>>6]=s; red[4+(tid>>6)]=s2; }
  __syncthreads();
  s  = red[0]+red[1]+red[2]+red[3];
  s2 = red[4]+red[5]+red[6]+red[7];
  const float mu = s*(1.f/1024.f);
  const float rs = rsqrtf(s2*(1.f/1024.f) - mu*mu + 1e-5f);
  #pragma unroll
  for (int i=0;i<4;i++){
    int k = tid + 256*i;
    lns[k] = (a4[i]-mu)*rs*lng[k] + lnb[k];
  }
  __syncthreads();
  const int c = tid&31;
  const int kq = tid>>5;               // 8-way k split, 128 each
  const int col = (blockIdx.x<<5) + c;
  float acc = 0.f;
  #pragma unroll 8
  for (int k=kq*128; k<kq*128+128; k++)
    acc = fmaf(lns[k], W1[(size_t)k*1024 + col], acc);
  cmb[c*8 + kq] = acc;
  __syncthreads();
  if (tid < 32){
    float v = b1[(blockIdx.x<<5) + tid];
    #pragma unroll
    for (int q=0;q<8;q++) v += cmb[tid*8 + q];
    hT[(size_t)((blockIdx.x<<5) + tid)*16 + b] = gelu_exact(v);
  }
}

// -------- K2: w[b][col] = h[b] . W2[:,col] + b2[col]  [16,32768] fp32 --------
__global__ __launch_bounds__(256) void k_hyper2(
    const float* __restrict__ hT, const float* __restrict__ W2, const float* __restrict__ b2,
    float* __restrict__ w)
{
  __shared__ float cmb[64*65];         // pad 65: write stride 65 floats -> conflict-free
  const int tid = threadIdx.x;
  const int c = tid&63;
  const int kq = tid>>6;               // == wave id, wave-uniform
  const int col = (blockIdx.x<<6) + c;
  const float* hbase = hT + (size_t)__builtin_amdgcn_readfirstlane(kq) * 256 * 16;
  float acc[16];
  #pragma unroll
  for (int i=0;i<16;i++) acc[i]=0.f;
  #pragma unroll 4
  for (int k=0;k<256;k++){
    float wv = W2[(size_t)(kq*256 + k)*32768 + col];
    const float* hk = hbase + k*16;    // uniform -> scalar loads
    #pragma unroll
    for (int bb=0;bb<16;bb++) acc[bb] = fmaf(hk[bb], wv, acc[bb]);
  }
  #pragma unroll
  for (int bb=0;bb<16;bb++) cmb[c*65 + kq*16 + bb] = acc[bb];
  __syncthreads();
  if (kq==0){
    float bv = b2[col];
    #pragma unroll
    for (int bb=0;bb<16;bb++)
      w[(size_t)bb*32768 + col] =
        cmb[c*65+bb] + cmb[c*65+16+bb] + cmb[c*65+32+bb] + cmb[c*65+48+bb] + bv;
  }
}

// -------- K3: fused LoRA chain + residual; fp32 in/out --------
// Factors in LDS as bf16 records [arr][d][8r]; lane reads d=l+64i -> 16B-stride b128, conflict-free.
// Spill control: round loop NOT unrolled; sched_barrier fences cap in-flight ld8 records
// at <=4 per array (original full-unroll hoisting hit the 256-VGPR cap and spilled ~300MB
// of scratch traffic per launch).
__global__ __launch_bounds__(256, 2) void k_lora(
    const float* __restrict__ x, const float* __restrict__ w, float* __restrict__ out)
{
  __shared__ __align__(16) u16 fsb[4*1024*8];   // 64 KB
  const int b = blockIdx.y;
  const int tid = threadIdx.x;
  const float* wb = w + (size_t)b*32768;
  // vectorized staging: float4 -> 4x bf16, 8B LDS write, 32 iters (was 128 scalar)
  {
    const float4* w4 = (const float4*)wb;
    #pragma unroll 4
    for (int j=0;j<32;j++){
      const int idx4 = tid + 256*j;
      float4 v = w4[idx4];
      union{u16 h[4]; u64 u;} pk;
      pk.h[0]=f2bf(v.x); pk.h[1]=f2bf(v.y);
      pk.h[2]=f2bf(v.z); pk.h[3]=f2bf(v.w);
      *(u64*)&fsb[idx4*4] = pk.u;
    }
  }
  __syncthreads();
  const int l = tid&63;
  const int wv = tid>>6;
  const uint4* fq = (const uint4*)fsb;
  const size_t xbase = (size_t)b*1024*1024;

  #pragma unroll 1
  for (int round=0; round<4; round++){
    const int t0 = blockIdx.x*32 + wv*8 + round*2;
    const float* xr = x + xbase + (size_t)t0*1024 + l;
    float xv0[16], xv1[16];
    #pragma unroll
    for (int i=0;i<16;i++){ xv0[i]=xr[64*i]; xv1[i]=xr[1024+64*i]; }

    // phase A: y1[t][r] = sum_d x_d * a1[d][r]
    float y10[8], y11[8];
    #pragma unroll
    for (int r=0;r<8;r++){ y10[r]=0.f; y11[r]=0.f; }
    #pragma unroll
    for (int i=0;i<16;i++){
      float a[8]; ld8(fq, 0, l+64*i, a);
      #pragma unroll
      for (int r=0;r<8;r++){
        y10[r] = fmaf(xv0[i], a[r], y10[r]);
        y11[r] = fmaf(xv1[i], a[r], y11[r]);
      }
      if ((i&3)==3) __builtin_amdgcn_sched_barrier(0);
    }
    #pragma unroll
    for (int m=32;m>=1;m>>=1){
      #pragma unroll
      for (int r=0;r<8;r++){
        y10[r] += __shfl_xor(y10[r], m, 64);
        y11[r] += __shfl_xor(y11[r], m, 64);
      }
    }

    // phase B: z_d = y1 . bb1[d]; y2[r] += gelu(z_d) * a2[d][r]   (p consumed before q loads)
    float y20[8], y21[8];
    #pragma unroll
    for (int r=0;r<8;r++){ y20[r]=0.f; y21[r]=0.f; }
    #pragma unroll
    for (int i=0;i<16;i++){
      float p[8]; ld8(fq, 1, l+64*i, p);
      float z0=0.f, z1=0.f;
      #pragma unroll
      for (int r=0;r<8;r++){ z0=fmaf(y10[r],p[r],z0); z1=fmaf(y11[r],p[r],z1); }
      float g0=gelu_exact(z0), g1=gelu_exact(z1);
      float q[8]; ld8(fq, 2, l+64*i, q);
      #pragma unroll
      for (int r=0;r<8;r++){ y20[r]=fmaf(g0,q[r],y20[r]); y21[r]=fmaf(g1,q[r],y21[r]); }
      if ((i&3)==3) __builtin_amdgcn_sched_barrier(0);
    }
    #pragma unroll
    for (int m=32;m>=1;m>>=1){
      #pragma unroll
      for (int r=0;r<8;r++){
        y20[r] += __shfl_xor(y20[r], m, 64);
        y21[r] += __shfl_xor(y21[r], m, 64);
      }
    }

    // phase C: out_d = x_d + y2 . bb2[d]
    #pragma unroll
    for (int i=0;i<16;i++){
      float cc[8]; ld8(fq, 3, l+64*i, cc);
      float o0 = xv0[i], o1 = xv1[i];
      #pragma unroll
      for (int r=0;r<8;r++){
        o0 = fmaf(y20[r], cc[r], o0);
        o1 = fmaf(y21[r], cc[r], o1);
      }
      out[xbase + (size_t)t0*1024 + l + 64*i] = o0;
      out[xbase + (size_t)(t0+1)*1024 + l + 64*i] = o1;
      if ((i&3)==3) __builtin_amdgcn_sched_barrier(0);
    }
  }
}

extern "C" void kernel_launch(void* const* d_in, const int* in_sizes, int n_in,
                              void* d_out, int out_size, void* d_ws, size_t ws_size,
                              hipStream_t stream){
  const float* x    = (const float*)d_in[0];
  const float* ada  = (const float*)d_in[1];
  const float* lng  = (const float*)d_in[2];
  const float* lnb  = (const float*)d_in[3];
  const float* W1   = (const float*)d_in[4];
  const float* b1   = (const float*)d_in[5];
  const float* W2   = (const float*)d_in[6];
  const float* b2   = (const float*)d_in[7];
  float* out = (float*)d_out;
  float* hT  = (float*)d_ws;                          // [1024,16] fp32 (64 KB)
  float* w   = (float*)((char*)d_ws + 65536);         // [16,32768] fp32 (2 MB)

  k_hyper1<<<dim3(32,16), 256, 0, stream>>>(ada, lng, lnb, W1, b1, hT);
  k_hyper2<<<dim3(512,1), 256, 0, stream>>>(hT, W2, b2, w);
  k_lora  <<<dim3(32,16), 256, 0, stream>>>(x, w, out);
}

// Round 2
// 296.418 us; speedup vs baseline: 1.8654x; 1.0289x over previous
//
#include <hip/hip_runtime.h>
#include <math.h>

typedef unsigned int u32;
typedef unsigned short u16;
typedef unsigned long long u64;

__device__ __forceinline__ u16 f2bf(float f){
  union{float f;u32 u;}v; v.f=f;
  u32 u=v.u; u += 0x7fffu + ((u>>16)&1u);
  return (u16)(u>>16);
}
__device__ __forceinline__ float gelu_exact(float z){
  return 0.5f*z*(1.f + erff(z*0.7071067811865476f));
}
// load 8 bf16 factors (one 16B record) from LDS at absolute slot, widen to fp32
__device__ __forceinline__ void ld8s(const uint4* fq, int slot, float* o){
  uint4 v = fq[slot];
  union{u32 i;float f;}c;
  c.i = v.x<<16;        o[0]=c.f;  c.i = v.x&0xffff0000u; o[1]=c.f;
  c.i = v.y<<16;        o[2]=c.f;  c.i = v.y&0xffff0000u; o[3]=c.f;
  c.i = v.z<<16;        o[4]=c.f;  c.i = v.z&0xffff0000u; o[5]=c.f;
  c.i = v.w<<16;        o[6]=c.f;  c.i = v.w&0xffff0000u; o[7]=c.f;
}

// -------- K1: hT[col][b] = gelu_exact( LN(ada[b]) @ W1 + b1 )[col]  [1024,16] fp32 --------
__global__ __launch_bounds__(256) void k_hyper1(
    const float* __restrict__ ada, const float* __restrict__ lng, const float* __restrict__ lnb,
    const float* __restrict__ W1, const float* __restrict__ b1, float* __restrict__ hT)
{
  __shared__ float lns[1024];
  __shared__ float red[8];
  __shared__ float cmb[256];
  const int b = blockIdx.y;
  const int tid = threadIdx.x;
  float a4[4]; float s=0.f, s2=0.f;
  #pragma unroll
  for (int i=0;i<4;i++){
    float v = ada[(size_t)b*1024 + tid + 256*i];
    a4[i]=v; s+=v; s2+=v*v;
  }
  #pragma unroll
  for (int m=32;m>=1;m>>=1){ s += __shfl_xor(s,m,64); s2 += __shfl_xor(s2,m,64); }
  if ((tid&63)==0){ red[tid>>6]=s; red[4+(tid>>6)]=s2; }
  __syncthreads();
  s  = red[0]+red[1]+red[2]+red[3];
  s2 = red[4]+red[5]+red[6]+red[7];
  const float mu = s*(1.f/1024.f);
  const float rs = rsqrtf(s2*(1.f/1024.f) - mu*mu + 1e-5f);
  #pragma unroll
  for (int i=0;i<4;i++){
    int k = tid + 256*i;
    lns[k] = (a4[i]-mu)*rs*lng[k] + lnb[k];
  }
  __syncthreads();
  const int c = tid&31;
  const int kq = tid>>5;               // 8-way k split, 128 each
  const int col = (blockIdx.x<<5) + c;
  float acc = 0.f;
  #pragma unroll 8
  for (int k=kq*128; k<kq*128+128; k++)
    acc = fmaf(lns[k], W1[(size_t)k*1024 + col], acc);
  cmb[c*8 + kq] = acc;
  __syncthreads();
  if (tid < 32){
    float v = b1[(blockIdx.x<<5) + tid];
    #pragma unroll
    for (int q=0;q<8;q++) v += cmb[tid*8 + q];
    hT[(size_t)((blockIdx.x<<5) + tid)*16 + b] = gelu_exact(v);
  }
}

// -------- K2: w16[b][slot][r] = bf16( h[b] . W2[:,col] + b2[col] )  [16][4096 rec][8] --------
// Output written as bf16 records in SWIZZLED slot order s(arr,d)=arr*1024+(d&3)*256+(d>>2)
// so k_lora stages with a pure uint4 copy (no conversion) and float4 x-loads stay
// bank-conflict-free on the LDS records.
__global__ __launch_bounds__(256) void k_hyper2(
    const float* __restrict__ hT, const float* __restrict__ W2, const float* __restrict__ b2,
    u16* __restrict__ w16)
{
  __shared__ float cmb[64*65];         // pad 65: write stride 65 floats -> conflict-free
  const int tid = threadIdx.x;
  const int c = tid&63;
  const int kq = tid>>6;               // == wave id, wave-uniform
  const int col = (blockIdx.x<<6) + c;
  const float* hbase = hT + (size_t)__builtin_amdgcn_readfirstlane(kq) * 256 * 16;
  float acc[16];
  #pragma unroll
  for (int i=0;i<16;i++) acc[i]=0.f;
  #pragma unroll 8
  for (int k=0;k<256;k++){
    float wv = W2[(size_t)(kq*256 + k)*32768 + col];
    const float* hk = hbase + k*16;    // uniform -> scalar loads
    #pragma unroll
    for (int bb=0;bb<16;bb++) acc[bb] = fmaf(hk[bb], wv, acc[bb]);
  }
  #pragma unroll
  for (int bb=0;bb<16;bb++) cmb[c*65 + kq*16 + bb] = acc[bb];
  __syncthreads();
  if (kq==0){
    float bv = b2[col];
    const int r   = col & 7;
    const int d   = (col >> 3) & 1023;
    const int arr = col >> 13;
    const int slot = (arr<<10) + ((d&3)<<8) + (d>>2);
    u16* wrec = w16 + ((size_t)slot<<3) + r;
    #pragma unroll
    for (int bb=0;bb<16;bb++){
      float v = cmb[c*65+bb] + cmb[c*65+16+bb] + cmb[c*65+32+bb] + cmb[c*65+48+bb] + bv;
      wrec[(size_t)bb*32768] = f2bf(v);
    }
  }
}

// -------- K3: fused LoRA chain + residual; fp32 in/out --------
// Factors pre-converted bf16, pre-swizzled by k_hyper2; staging = pure 64KB copy.
// x/out accessed as float4: lane l, i covers d = 4*(l+64i)+c, matching record slot
// arr*1024 + c*256 + i*64 + l (lane-stride 16B -> conflict-free ds_read_b128).
__global__ __launch_bounds__(256, 2) void k_lora(
    const float* __restrict__ x, const u16* __restrict__ w16, float* __restrict__ out)
{
  __shared__ __align__(16) u16 fsb[4*1024*8];   // 64 KB
  const int b = blockIdx.y;
  const int tid = threadIdx.x;
  {
    const uint4* src = (const uint4*)(w16 + (size_t)b*32768);
    uint4* dst = (uint4*)fsb;
    #pragma unroll 4
    for (int j=0;j<16;j++) dst[tid + 256*j] = src[tid + 256*j];
  }
  __syncthreads();
  const int l = tid&63;
  const int wv = tid>>6;
  const uint4* fq = (const uint4*)fsb;
  const size_t xb4 = ((size_t)b<<18);           // float4 base: b*1024*1024/4

  #pragma unroll 1
  for (int round=0; round<4; round++){
    const int t0 = blockIdx.x*32 + wv*8 + round*2;
    const float4* xr = (const float4*)x + xb4 + ((size_t)t0<<8) + l;
    float4 xv0[4], xv1[4];
    #pragma unroll
    for (int i=0;i<4;i++){ xv0[i]=xr[64*i]; xv1[i]=xr[256+64*i]; }

    // phase A: y1[t][r] = sum_d x_d * a1[d][r]
    float y10[8], y11[8];
    #pragma unroll
    for (int r=0;r<8;r++){ y10[r]=0.f; y11[r]=0.f; }
    #pragma unroll
    for (int i=0;i<4;i++){
      const int sb = 64*i + l;
      const float xc0[4] = {xv0[i].x, xv0[i].y, xv0[i].z, xv0[i].w};
      const float xc1[4] = {xv1[i].x, xv1[i].y, xv1[i].z, xv1[i].w};
      #pragma unroll
      for (int cc=0;cc<4;cc++){
        float a[8]; ld8s(fq, cc*256 + sb, a);
        #pragma unroll
        for (int r=0;r<8;r++){
          y10[r] = fmaf(xc0[cc], a[r], y10[r]);
          y11[r] = fmaf(xc1[cc], a[r], y11[r]);
        }
      }
      __builtin_amdgcn_sched_barrier(0);
    }
    #pragma unroll
    for (int m=32;m>=1;m>>=1){
      #pragma unroll
      for (int r=0;r<8;r++){
        y10[r] += __shfl_xor(y10[r], m, 64);
        y11[r] += __shfl_xor(y11[r], m, 64);
      }
    }

    // phase B: z_d = y1 . bb1[d]; y2[r] += gelu(z_d) * a2[d][r]
    float y20[8], y21[8];
    #pragma unroll
    for (int r=0;r<8;r++){ y20[r]=0.f; y21[r]=0.f; }
    #pragma unroll
    for (int i=0;i<4;i++){
      const int sb = 64*i + l;
      #pragma unroll
      for (int cc=0;cc<4;cc++){
        float p[8]; ld8s(fq, 1024 + cc*256 + sb, p);
        float z0=0.f, z1=0.f;
        #pragma unroll
        for (int r=0;r<8;r++){ z0=fmaf(y10[r],p[r],z0); z1=fmaf(y11[r],p[r],z1); }
        float g0=gelu_exact(z0), g1=gelu_exact(z1);
        float q[8]; ld8s(fq, 2048 + cc*256 + sb, q);
        #pragma unroll
        for (int r=0;r<8;r++){ y20[r]=fmaf(g0,q[r],y20[r]); y21[r]=fmaf(g1,q[r],y21[r]); }
        __builtin_amdgcn_sched_barrier(0);
      }
    }
    #pragma unroll
    for (int m=32;m>=1;m>>=1){
      #pragma unroll
      for (int r=0;r<8;r++){
        y20[r] += __shfl_xor(y20[r], m, 64);
        y21[r] += __shfl_xor(y21[r], m, 64);
      }
    }

    // phase C: out_d = x_d + y2 . bb2[d]
    float4* op = (float4*)out + xb4 + ((size_t)t0<<8) + l;
    #pragma unroll
    for (int i=0;i<4;i++){
      const int sb = 64*i + l;
      float4 o0 = xv0[i], o1 = xv1[i];
      float o0c[4] = {o0.x,o0.y,o0.z,o0.w};
      float o1c[4] = {o1.x,o1.y,o1.z,o1.w};
      #pragma unroll
      for (int cc=0;cc<4;cc++){
        float ccf[8]; ld8s(fq, 3072 + cc*256 + sb, ccf);
        #pragma unroll
        for (int r=0;r<8;r++){
          o0c[cc] = fmaf(y20[r], ccf[r], o0c[cc]);
          o1c[cc] = fmaf(y21[r], ccf[r], o1c[cc]);
        }
      }
      o0.x=o0c[0]; o0.y=o0c[1]; o0.z=o0c[2]; o0.w=o0c[3];
      o1.x=o1c[0]; o1.y=o1c[1]; o1.z=o1c[2]; o1.w=o1c[3];
      op[64*i] = o0;
      op[256+64*i] = o1;
      __builtin_amdgcn_sched_barrier(0);
    }
  }
}

extern "C" void kernel_launch(void* const* d_in, const int* in_sizes, int n_in,
                              void* d_out, int out_size, void* d_ws, size_t ws_size,
                              hipStream_t stream){
  const float* x    = (const float*)d_in[0];
  const float* ada  = (const float*)d_in[1];
  const float* lng  = (const float*)d_in[2];
  const float* lnb  = (const float*)d_in[3];
  const float* W1   = (const float*)d_in[4];
  const float* b1   = (const float*)d_in[5];
  const float* W2   = (const float*)d_in[6];
  const float* b2   = (const float*)d_in[7];
  float* out = (float*)d_out;
  float* hT  = (float*)d_ws;                          // [1024,16] fp32 (64 KB)
  u16*   w16 = (u16*)((char*)d_ws + 65536);           // [16][4096 rec][8 r] bf16 (1 MB)

  k_hyper1<<<dim3(32,16), 256, 0, stream>>>(ada, lng, lnb, W1, b1, hT);
  k_hyper2<<<dim3(512,1), 256, 0, stream>>>(hT, W2, b2, w16);
  k_lora  <<<dim3(32,16), 256, 0, stream>>>(x, w16, out);
}